// Round 1
// baseline (251.448 us; speedup 1.0000x reference)
//
#include <hip/hip_runtime.h>

#define N_CELLTYPE 50
#define M_PER_CT   2000
#define N_FEATURE  20000
#define N_CELL     512
#define R_TOTAL    (N_CELLTYPE * M_PER_CT)   // 100000 rows of z
#define TR         32                        // rows per tile  (100000/32 = 3125 exact)
#define TC         128                       // cols per tile  (512/128 = 4 exact)

// Gather + scale + transpose via LDS tile.
//   read : x[idx[r]][c0..c0+127]  -> float4-coalesced (x rows contiguous)
//   write: out[(c0+c)*100000 + r0..r0+31] -> float4-coalesced, 128B aligned segs
__global__ __launch_bounds__(256) void ct_scale_transpose(
    const float* __restrict__ x, const float* __restrict__ w,
    const int* __restrict__ idx, float* __restrict__ out) {
  // +4 pad keeps each row's base 16B-aligned for ds_write_b128 while
  // breaking the power-of-2 stride for the transposed read.
  __shared__ float tile[TR][TC + 4];
  __shared__ int   srow[TR];
  __shared__ float sw[TR];

  const int r0 = blockIdx.x * TR;
  const int c0 = blockIdx.y * TC;
  const int t  = threadIdx.x;

  // Stage the 32 gather indices + per-row weights once per block.
  if (t < TR) {
    const int r = r0 + t;
    srow[t] = idx[r];
    sw[t]   = w[r / M_PER_CT];
  }
  __syncthreads();

  // Load phase: 32 rows x 32 float4 = 1024 float4, 4 per thread.
#pragma unroll
  for (int i = 0; i < 4; ++i) {
    const int linear = i * 256 + t;
    const int row = linear >> 5;    // 0..31
    const int q   = linear & 31;    // float4 index within row (cols q*4..q*4+3)
    const float4 v = *reinterpret_cast<const float4*>(
        x + (long)srow[row] * N_CELL + c0 + q * 4);
    const float s = sw[row];
    float4 sv;
    sv.x = v.x * s; sv.y = v.y * s; sv.z = v.z * s; sv.w = v.w * s;
    *reinterpret_cast<float4*>(&tile[row][q * 4]) = sv;
  }
  __syncthreads();

  // Store phase: 128 cols x 8 float4 (32 r each) = 1024 float4, 4 per thread.
#pragma unroll
  for (int i = 0; i < 4; ++i) {
    const int linear = i * 256 + t;
    const int c  = linear >> 3;     // 0..127
    const int q  = linear & 7;      // which 4-row chunk
    const int rr = q * 4;
    float4 v;
    v.x = tile[rr + 0][c];
    v.y = tile[rr + 1][c];
    v.z = tile[rr + 2][c];
    v.w = tile[rr + 3][c];
    *reinterpret_cast<float4*>(out + (long)(c0 + c) * R_TOTAL + r0 + rr) = v;
  }
}

extern "C" void kernel_launch(void* const* d_in, const int* in_sizes, int n_in,
                              void* d_out, int out_size, void* d_ws, size_t ws_size,
                              hipStream_t stream) {
  const float* x   = (const float*)d_in[0];
  const float* w   = (const float*)d_in[1];
  const int*   idx = (const int*)d_in[2];
  float*       out = (float*)d_out;

  dim3 grid(R_TOTAL / TR, N_CELL / TC);   // 3125 x 4 = 12500 blocks
  ct_scale_transpose<<<grid, 256, 0, stream>>>(x, w, idx, out);
}

// Round 3
// 246.667 us; speedup vs baseline: 1.0194x; 1.0194x over previous
//
#include <hip/hip_runtime.h>

#define N_CELLTYPE 50
#define M_PER_CT   2000
#define N_FEATURE  20000
#define N_CELL     512
#define R_TOTAL    (N_CELLTYPE * M_PER_CT)   // 100000 rows of z
#define TR         32                        // rows per tile  (100000/32 = 3125 exact)
#define TC         256                       // cols per tile  (512/256 = 2 exact)
#define NTHREADS   512

typedef float vfloat4 __attribute__((ext_vector_type(4)));  // native vec for nt-store

// Gather + scale + transpose via LDS tile.
//   read : x[idx[r]][c0..c0+255]  -> wave reads 1KB contiguous per instr
//   write: out[(c0+c)*100000 + r0..r0+31] -> 128B full-line aligned segments,
//          nontemporal so the 205MB write stream doesn't evict the gather
//          working set of x from L2 (dup rows have ~5x reuse).
__global__ __launch_bounds__(NTHREADS) void ct_scale_transpose(
    const float* __restrict__ x, const float* __restrict__ w,
    const int* __restrict__ idx, float* __restrict__ out) {
  // +4 pad: row base stays 16B-aligned for b128 writes; transposed b32 reads
  // land on 16 banks (4-way) instead of 8 banks (8-way).
  __shared__ float tile[TR][TC + 4];
  __shared__ int   srow[TR];
  __shared__ float sw[TR];

  const int r0 = blockIdx.x * TR;
  const int c0 = blockIdx.y * TC;
  const int t  = threadIdx.x;

  if (t < TR) {
    const int r = r0 + t;
    srow[t] = idx[r];
    sw[t]   = w[r / M_PER_CT];
  }
  __syncthreads();

  // Load phase: 32 rows x 64 float4 = 2048 float4, 4 per thread.
  // Each wave-instr: one whole row, 64 consecutive float4 = 1KB contiguous.
#pragma unroll
  for (int i = 0; i < 4; ++i) {
    const int linear = i * NTHREADS + t;
    const int row = linear >> 6;    // 0..31
    const int q   = linear & 63;    // float4 index within row
    const float4 v = *reinterpret_cast<const float4*>(
        x + (long)srow[row] * N_CELL + c0 + q * 4);
    const float s = sw[row];
    float4 sv;
    sv.x = v.x * s; sv.y = v.y * s; sv.z = v.z * s; sv.w = v.w * s;
    *reinterpret_cast<float4*>(&tile[row][q * 4]) = sv;
  }
  __syncthreads();

  // Store phase: 256 cols x 8 float4 (32 r each) = 2048 float4, 4 per thread.
#pragma unroll
  for (int i = 0; i < 4; ++i) {
    const int linear = i * NTHREADS + t;
    const int c  = linear >> 3;     // 0..255
    const int q  = linear & 7;      // which 4-row chunk
    const int rr = q * 4;
    vfloat4 v;
    v.x = tile[rr + 0][c];
    v.y = tile[rr + 1][c];
    v.z = tile[rr + 2][c];
    v.w = tile[rr + 3][c];
    __builtin_nontemporal_store(
        v, reinterpret_cast<vfloat4*>(out + (long)(c0 + c) * R_TOTAL + r0 + rr));
  }
}

extern "C" void kernel_launch(void* const* d_in, const int* in_sizes, int n_in,
                              void* d_out, int out_size, void* d_ws, size_t ws_size,
                              hipStream_t stream) {
  const float* x   = (const float*)d_in[0];
  const float* w   = (const float*)d_in[1];
  const int*   idx = (const int*)d_in[2];
  float*       out = (float*)d_out;

  dim3 grid(R_TOTAL / TR, N_CELL / TC);   // 3125 x 2 = 6250 blocks
  ct_scale_transpose<<<grid, NTHREADS, 0, stream>>>(x, w, idx, out);
}